// Round 2
// baseline (4863.719 us; speedup 1.0000x reference)
//
#include <hip/hip_runtime.h>
#include <hip/hip_bf16.h>
#include <math.h>

// Problem constants (from reference setup_inputs)
#define BB 4
#define SS 512
#define HH 2048
#define EE 16
#define DD 128
#define GH 2048           // E*D
#define G3 6144           // 3*GH
#define NTOK 2048         // B*S

#define LSTR 132          // LDS leading-dim pad for 128-wide fp32 tiles
#define FPAD 32           // flag padding: one flag per 128 B
#define KS 40             // bf16 LDS row stride in shorts (32 + 8 pad)

typedef __attribute__((ext_vector_type(8))) short short8;   // 8 bf16 = 4 VGPR
typedef __attribute__((ext_vector_type(4))) float f32x4;    // MFMA C/D

// ---------------- GEMM 1 (fp32): C[M,N] = A[M,K] * B[N,K]^T ------------------
// xi = x @ w_ih^T. Kept fp32: xi feeds the chaotic GRU recurrence (absmax
// 0.0156 from fp32-level seeds implies ~1e4 amplification; bf16 here would
// blow the threshold). Tile 128x128, BK=8, 8x8/thread.
__global__ __launch_bounds__(256) void gemm_abt(const float* __restrict__ A,
                                                const float* __restrict__ B,
                                                float* __restrict__ C,
                                                int M, int N, int K) {
  __shared__ float As[8][LSTR];
  __shared__ float Bs[8][LSTR];
  const int bm = blockIdx.y * 128, bn = blockIdx.x * 128;
  const int tid = threadIdx.x;
  const int lm = tid >> 1;
  const int kh = (tid & 1) * 4;
  const int tx = tid & 15, ty = tid >> 4;
  float acc[8][8] = {};
  const float* Arow = A + (size_t)(bm + lm) * K + kh;
  const float* Brow = B + (size_t)(bn + lm) * K + kh;
  for (int k0 = 0; k0 < K; k0 += 8) {
    float4 av = *(const float4*)(Arow + k0);
    float4 bv = *(const float4*)(Brow + k0);
    As[kh + 0][lm] = av.x; As[kh + 1][lm] = av.y; As[kh + 2][lm] = av.z; As[kh + 3][lm] = av.w;
    Bs[kh + 0][lm] = bv.x; Bs[kh + 1][lm] = bv.y; Bs[kh + 2][lm] = bv.z; Bs[kh + 3][lm] = bv.w;
    __syncthreads();
#pragma unroll
    for (int kk = 0; kk < 8; ++kk) {
      float a8[8], b8[8];
      *(float4*)(a8)     = *(const float4*)(&As[kk][ty * 8]);
      *(float4*)(a8 + 4) = *(const float4*)(&As[kk][ty * 8 + 4]);
      *(float4*)(b8)     = *(const float4*)(&Bs[kk][tx * 8]);
      *(float4*)(b8 + 4) = *(const float4*)(&Bs[kk][tx * 8 + 4]);
#pragma unroll
      for (int i = 0; i < 8; ++i)
#pragma unroll
        for (int j = 0; j < 8; ++j) acc[i][j] = fmaf(a8[i], b8[j], acc[i][j]);
    }
    __syncthreads();
  }
#pragma unroll
  for (int i = 0; i < 8; ++i) {
    float4 v0 = {acc[i][0], acc[i][1], acc[i][2], acc[i][3]};
    float4 v1 = {acc[i][4], acc[i][5], acc[i][6], acc[i][7]};
    float* crow = C + (size_t)(bm + ty * 8 + i) * N + bn + tx * 8;
    *(float4*)(crow)     = v0;
    *(float4*)(crow + 4) = v1;
  }
}

// ---------------- fp32 fallbacks (used only if ws too small) -----------------
__global__ __launch_bounds__(256) void gemm_ab(const float* __restrict__ A,
                                               const float* __restrict__ B,
                                               float* __restrict__ C,
                                               int M, int N, int K) {
  __shared__ float As[8][LSTR];
  __shared__ float Bs[8][LSTR];
  const int bm = blockIdx.y * 128, bn = blockIdx.x * 128;
  const int tid = threadIdx.x;
  const int lm = tid >> 1;
  const int kh = (tid & 1) * 4;
  const int bk = tid >> 5;
  const int bn4 = (tid & 31) * 4;
  const int tx = tid & 15, ty = tid >> 4;
  float acc[8][8] = {};
  const float* Arow = A + (size_t)(bm + lm) * K + kh;
  for (int k0 = 0; k0 < K; k0 += 8) {
    float4 av = *(const float4*)(Arow + k0);
    float4 bv = *(const float4*)(B + (size_t)(k0 + bk) * N + bn + bn4);
    As[kh + 0][lm] = av.x; As[kh + 1][lm] = av.y; As[kh + 2][lm] = av.z; As[kh + 3][lm] = av.w;
    *(float4*)(&Bs[bk][bn4]) = bv;
    __syncthreads();
#pragma unroll
    for (int kk = 0; kk < 8; ++kk) {
      float a8[8], b8[8];
      *(float4*)(a8)     = *(const float4*)(&As[kk][ty * 8]);
      *(float4*)(a8 + 4) = *(const float4*)(&As[kk][ty * 8 + 4]);
      *(float4*)(b8)     = *(const float4*)(&Bs[kk][tx * 8]);
      *(float4*)(b8 + 4) = *(const float4*)(&Bs[kk][tx * 8 + 4]);
#pragma unroll
      for (int i = 0; i < 8; ++i)
#pragma unroll
        for (int j = 0; j < 8; ++j) acc[i][j] = fmaf(a8[i], b8[j], acc[i][j]);
    }
    __syncthreads();
  }
#pragma unroll
  for (int i = 0; i < 8; ++i) {
    float4 v0 = {acc[i][0], acc[i][1], acc[i][2], acc[i][3]};
    float4 v1 = {acc[i][4], acc[i][5], acc[i][6], acc[i][7]};
    float* crow = C + (size_t)(bm + ty * 8 + i) * N + bn + tx * 8;
    *(float4*)(crow)     = v0;
    *(float4*)(crow + 4) = v1;
  }
}

__global__ __launch_bounds__(256) void ata_loss(const float* __restrict__ A,
                                                float* __restrict__ el_accum,
                                                int N, int K) {
  __shared__ float As[8][LSTR];
  __shared__ float Bs[8][LSTR];
  __shared__ float red[256];
  const int bi = blockIdx.y * 128, bj = blockIdx.x * 128;
  const int tid = threadIdx.x;
  const int bk = tid >> 5;
  const int bn4 = (tid & 31) * 4;
  const int tx = tid & 15, ty = tid >> 4;
  float acc[8][8] = {};
  for (int k0 = 0; k0 < K; k0 += 8) {
    float4 av = *(const float4*)(A + (size_t)(k0 + bk) * N + bi + bn4);
    float4 bv = *(const float4*)(A + (size_t)(k0 + bk) * N + bj + bn4);
    *(float4*)(&As[bk][bn4]) = av;
    *(float4*)(&Bs[bk][bn4]) = bv;
    __syncthreads();
#pragma unroll
    for (int kk = 0; kk < 8; ++kk) {
      float a8[8], b8[8];
      *(float4*)(a8)     = *(const float4*)(&As[kk][ty * 8]);
      *(float4*)(a8 + 4) = *(const float4*)(&As[kk][ty * 8 + 4]);
      *(float4*)(b8)     = *(const float4*)(&Bs[kk][tx * 8]);
      *(float4*)(b8 + 4) = *(const float4*)(&Bs[kk][tx * 8 + 4]);
#pragma unroll
      for (int i = 0; i < 8; ++i)
#pragma unroll
        for (int j = 0; j < 8; ++j) acc[i][j] = fmaf(a8[i], b8[j], acc[i][j]);
    }
    __syncthreads();
  }
  float local = 0.f;
#pragma unroll
  for (int i = 0; i < 8; ++i) {
#pragma unroll
    for (int j = 0; j < 8; ++j) {
      int gi = bi + ty * 8 + i, gj = bj + tx * 8 + j;
      float d = acc[i][j] - ((gi == gj) ? 1.0f : 0.0f);
      local += d * d;
    }
  }
  red[tid] = local;
  __syncthreads();
  for (int s = 128; s > 0; s >>= 1) {
    if (tid < s) red[tid] += red[tid + s];
    __syncthreads();
  }
  if (tid == 0) atomicAdd(el_accum, red[0]);
}

// ---------------- split-bf16 helpers -----------------------------------------
__device__ inline void bf16_split(float v, unsigned short& hi, unsigned short& lo) {
  unsigned u = __float_as_uint(v);
  unsigned r = u + 0x7FFFu + ((u >> 16) & 1u);   // RTN-even to bf16
  hi = (unsigned short)(r >> 16);
  float rem = v - __uint_as_float((unsigned)hi << 16);  // exact (Sterbenz)
  lo = (unsigned short)(__float_as_uint(rem) >> 16);    // truncate remainder
}

__global__ __launch_bounds__(256) void split_mat(const float* __restrict__ A,
                                                 unsigned short* __restrict__ Hh,
                                                 unsigned short* __restrict__ Hl,
                                                 int n) {
  int i = blockIdx.x * 256 + threadIdx.x;
  int stride = gridDim.x * 256;
  for (; i < n; i += stride) {
    unsigned short hi, lo;
    bf16_split(A[i], hi, lo);
    Hh[i] = hi; Hl[i] = lo;
  }
}

// w_expr [H][GH] -> transposed split T[GH][H] (hi/lo bf16)
__global__ __launch_bounds__(256) void transpose_split(const float* __restrict__ A,
                                                       unsigned short* __restrict__ Th,
                                                       unsigned short* __restrict__ Tl) {
  __shared__ float tile[64][65];
  const int bx = blockIdx.x * 64, by = blockIdx.y * 64;  // bx: n, by: k
  const int tx = threadIdx.x & 63, ty = threadIdx.x >> 6;
#pragma unroll
  for (int i = 0; i < 16; ++i) {
    int r = ty + i * 4;
    tile[r][tx] = A[(size_t)(by + r) * GH + bx + tx];
  }
  __syncthreads();
#pragma unroll
  for (int i = 0; i < 16; ++i) {
    int r = ty + i * 4;                 // output row n = bx + r; col k = by + tx
    unsigned short hi, lo;
    bf16_split(tile[tx][r], hi, lo);
    Th[(size_t)(bx + r) * HH + by + tx] = hi;
    Tl[(size_t)(bx + r) * HH + by + tx] = lo;
  }
}

// ---------------- split-bf16 MFMA GEMM: C[M,N] = A[M,K]*B[N,K]^T -------------
// A,B given as bf16 (hi,lo); acc = Ah*Bh + Ah*Bl + Al*Bh (drop Al*Bl ~2^-18).
// 128x128 tile, BK=32 (one 16x16x32 MFMA k-step), 4 waves x 64x64 quadrant,
// padded LDS stride (KS=40 shorts) -> <=2-way bank conflicts (free per m136).
__global__ __launch_bounds__(256) void gemm_abt_bf16(
    const unsigned short* __restrict__ Ah, const unsigned short* __restrict__ Al,
    const unsigned short* __restrict__ Bh, const unsigned short* __restrict__ Bl,
    float* __restrict__ C, int M, int N, int K) {
  __shared__ unsigned short Ahs[128 * KS], Als[128 * KS];
  __shared__ unsigned short Bhs[128 * KS], Bls[128 * KS];
  const int tid = threadIdx.x;
  const int wv = tid >> 6, lane = tid & 63;
  const int qr = wv >> 1, qc = wv & 1;
  const int m16 = lane & 15, q = lane >> 4;
  const int bm = blockIdx.y * 128, bn = blockIdx.x * 128;
  const int sr = tid >> 1, sh = (tid & 1) * 16;   // staging: row, k-half
  f32x4 zero = {0.f, 0.f, 0.f, 0.f};
  f32x4 acc[4][4];
#pragma unroll
  for (int i = 0; i < 4; ++i)
#pragma unroll
    for (int j = 0; j < 4; ++j) acc[i][j] = zero;

  for (int k0 = 0; k0 < K; k0 += 32) {
    const size_t ga = (size_t)(bm + sr) * K + k0 + sh;
    const size_t gb = (size_t)(bn + sr) * K + k0 + sh;
    short8 a0 = *(const short8*)(Ah + ga);
    short8 a1 = *(const short8*)(Ah + ga + 8);
    short8 l0 = *(const short8*)(Al + ga);
    short8 l1 = *(const short8*)(Al + ga + 8);
    short8 b0 = *(const short8*)(Bh + gb);
    short8 b1 = *(const short8*)(Bh + gb + 8);
    short8 m0 = *(const short8*)(Bl + gb);
    short8 m1 = *(const short8*)(Bl + gb + 8);
    __syncthreads();   // previous iter's frag reads complete
    *(short8*)&Ahs[sr * KS + sh]     = a0;
    *(short8*)&Ahs[sr * KS + sh + 8] = a1;
    *(short8*)&Als[sr * KS + sh]     = l0;
    *(short8*)&Als[sr * KS + sh + 8] = l1;
    *(short8*)&Bhs[sr * KS + sh]     = b0;
    *(short8*)&Bhs[sr * KS + sh + 8] = b1;
    *(short8*)&Bls[sr * KS + sh]     = m0;
    *(short8*)&Bls[sr * KS + sh + 8] = m1;
    __syncthreads();
    short8 afh[4], afl[4], bfh[4], bfl[4];
#pragma unroll
    for (int t = 0; t < 4; ++t) {
      const int raddr = (qr * 64 + t * 16 + m16) * KS + q * 8;
      const int caddr = (qc * 64 + t * 16 + m16) * KS + q * 8;
      afh[t] = *(const short8*)&Ahs[raddr];
      afl[t] = *(const short8*)&Als[raddr];
      bfh[t] = *(const short8*)&Bhs[caddr];
      bfl[t] = *(const short8*)&Bls[caddr];
    }
#pragma unroll
    for (int tm = 0; tm < 4; ++tm)
#pragma unroll
      for (int tn = 0; tn < 4; ++tn) {
        acc[tm][tn] = __builtin_amdgcn_mfma_f32_16x16x32_bf16(afh[tm], bfh[tn], acc[tm][tn], 0, 0, 0);
        acc[tm][tn] = __builtin_amdgcn_mfma_f32_16x16x32_bf16(afh[tm], bfl[tn], acc[tm][tn], 0, 0, 0);
        acc[tm][tn] = __builtin_amdgcn_mfma_f32_16x16x32_bf16(afl[tm], bfh[tn], acc[tm][tn], 0, 0, 0);
      }
  }
  // C/D layout: col = lane&15, row = (lane>>4)*4 + reg  [m89-verified]
#pragma unroll
  for (int tm = 0; tm < 4; ++tm)
#pragma unroll
    for (int tn = 0; tn < 4; ++tn)
#pragma unroll
      for (int r = 0; r < 4; ++r)
        C[(size_t)(bm + qr * 64 + tm * 16 + q * 4 + r) * N +
          bn + qc * 64 + tn * 16 + m16] = acc[tm][tn][r];
}

// same mainloop, A=B=w_exprT; epilogue reduces (g - I)^2 instead of writing C
__global__ __launch_bounds__(256) void ata_bf16(
    const unsigned short* __restrict__ Th, const unsigned short* __restrict__ Tl,
    float* __restrict__ el_accum, int N, int K) {
  __shared__ unsigned short Ahs[128 * KS], Als[128 * KS];
  __shared__ unsigned short Bhs[128 * KS], Bls[128 * KS];
  __shared__ float red[256];
  const int tid = threadIdx.x;
  const int wv = tid >> 6, lane = tid & 63;
  const int qr = wv >> 1, qc = wv & 1;
  const int m16 = lane & 15, q = lane >> 4;
  const int bi = blockIdx.y * 128, bj = blockIdx.x * 128;
  const int sr = tid >> 1, sh = (tid & 1) * 16;
  f32x4 zero = {0.f, 0.f, 0.f, 0.f};
  f32x4 acc[4][4];
#pragma unroll
  for (int i = 0; i < 4; ++i)
#pragma unroll
    for (int j = 0; j < 4; ++j) acc[i][j] = zero;

  for (int k0 = 0; k0 < K; k0 += 32) {
    const size_t ga = (size_t)(bi + sr) * K + k0 + sh;
    const size_t gb = (size_t)(bj + sr) * K + k0 + sh;
    short8 a0 = *(const short8*)(Th + ga);
    short8 a1 = *(const short8*)(Th + ga + 8);
    short8 l0 = *(const short8*)(Tl + ga);
    short8 l1 = *(const short8*)(Tl + ga + 8);
    short8 b0 = *(const short8*)(Th + gb);
    short8 b1 = *(const short8*)(Th + gb + 8);
    short8 m0 = *(const short8*)(Tl + gb);
    short8 m1 = *(const short8*)(Tl + gb + 8);
    __syncthreads();
    *(short8*)&Ahs[sr * KS + sh]     = a0;
    *(short8*)&Ahs[sr * KS + sh + 8] = a1;
    *(short8*)&Als[sr * KS + sh]     = l0;
    *(short8*)&Als[sr * KS + sh + 8] = l1;
    *(short8*)&Bhs[sr * KS + sh]     = b0;
    *(short8*)&Bhs[sr * KS + sh + 8] = b1;
    *(short8*)&Bls[sr * KS + sh]     = m0;
    *(short8*)&Bls[sr * KS + sh + 8] = m1;
    __syncthreads();
    short8 afh[4], afl[4], bfh[4], bfl[4];
#pragma unroll
    for (int t = 0; t < 4; ++t) {
      const int raddr = (qr * 64 + t * 16 + m16) * KS + q * 8;
      const int caddr = (qc * 64 + t * 16 + m16) * KS + q * 8;
      afh[t] = *(const short8*)&Ahs[raddr];
      afl[t] = *(const short8*)&Als[raddr];
      bfh[t] = *(const short8*)&Bhs[caddr];
      bfl[t] = *(const short8*)&Bls[caddr];
    }
#pragma unroll
    for (int tm = 0; tm < 4; ++tm)
#pragma unroll
      for (int tn = 0; tn < 4; ++tn) {
        acc[tm][tn] = __builtin_amdgcn_mfma_f32_16x16x32_bf16(afh[tm], bfh[tn], acc[tm][tn], 0, 0, 0);
        acc[tm][tn] = __builtin_amdgcn_mfma_f32_16x16x32_bf16(afh[tm], bfl[tn], acc[tm][tn], 0, 0, 0);
        acc[tm][tn] = __builtin_amdgcn_mfma_f32_16x16x32_bf16(afl[tm], bfh[tn], acc[tm][tn], 0, 0, 0);
      }
  }
  float local = 0.f;
#pragma unroll
  for (int tm = 0; tm < 4; ++tm)
#pragma unroll
    for (int tn = 0; tn < 4; ++tn)
#pragma unroll
      for (int r = 0; r < 4; ++r) {
        int gi = bi + qr * 64 + tm * 16 + q * 4 + r;
        int gj = bj + qc * 64 + tn * 16 + m16;
        float d = acc[tm][tn][r] - ((gi == gj) ? 1.0f : 0.0f);
        local += d * d;
      }
  red[tid] = local;
  __syncthreads();
  for (int s = 128; s > 0; s >>= 1) {
    if (tid < s) red[tid] += red[tid + s];
    __syncthreads();
  }
  if (tid == 0) atomicAdd(el_accum, red[0]);
}

// ---------------- persistent GRU: line-granular flag dataflow ----------------
// Wave reduction: 4 DPP row_ror stages (VALU pipe, 16-lane rotate-reduce) +
// 2 shuffles for the cross-row halves. Replaces 6 ds_swizzle stages -> moves
// 48 of 72 LDS-unit ops per wave per step onto the underused VALU pipe.
// DPP ctrl must be a compile-time constant -> template parameter.
template <int CTRL>
__device__ inline float dpp_add(float v) {
  int t = __builtin_amdgcn_update_dpp(0, __float_as_int(v), CTRL, 0xf, 0xf, false);
  return v + __int_as_float(t);
}
__device__ inline float wred64(float v) {
  v = dpp_add<0x121>(v);   // row_ror:1
  v = dpp_add<0x122>(v);   // row_ror:2
  v = dpp_add<0x124>(v);   // row_ror:4
  v = dpp_add<0x128>(v);   // row_ror:8  -> every lane has its 16-row sum
  v += __shfl_xor(v, 16);
  v += __shfl_xor(v, 32);
  return v;
}

// hsm slot swizzle: the float4 {h[0..3][k]} for column k lives at 16B-slot
//   sigma(k) = (k & ~63) | ((k & 3) << 4) | ((k >> 2) & 15)
// Read (lane l, iter c): slot c*64 + sigma_l, sigma_l = ((l&3)<<4)|(l>>2) —
//   bijection per 64-group, each bank hit exactly 8x (b128 minimum).
// Restage write (thread t, i=0..3): slot ((t>>4)<<6)|(i<<4)|(t&15) — per
//   instruction lanes cover 4 dense 16-slot runs, again bank-minimal.
// (Old linear layout: restage writes strided 64 B -> 8 banks for 64 lanes,
//  the source of the 1.0e8 SQ_LDS_BANK_CONFLICT.)
//
// 256 blocks x 512 threads, cooperative. Wave w of block p owns column
// j = p*8+w; its 3 w_hh rows live in registers (lane-strided k).
// State layout hsx[s][p][b][8]: block p's per-step output is EXACTLY one
// 128 B line -> line-granular validity. NEW publish protocol (replaces
// store -> block barrier -> tid0 flag): hsm is double-buffered, so the
// pre-publish block barrier is gone. Each wave drains its OWN h stores
// (s_waitcnt vmcnt(0)), arrives on an LDS counter; the 8th arriver stores
// the per-block flag (monotone s+1). Invariant preserved: flag is stored
// only after all 8 waves' stores are ack'd at L3. Fast waves poll+load
// consumer lines while slow waves are still computing (overlap). One
// block barrier per step (after restage) protects the hsm ping-pong:
// any read of buf X in step s is separated from the next write of buf X
// (step s+2) by the step-s barrier.
__global__ __launch_bounds__(512, 2) void gru_persistent(
    const float* __restrict__ xi,    // [B,S,3GH]
    const float* __restrict__ w_hh,  // [3GH,GH]
    const float* __restrict__ hn,    // [B,GH]
    float* __restrict__ hsx,         // [S][256][4][8]
    int* __restrict__ flags) {       // [256*FPAD], zeroed
  __shared__ __align__(16) float hsm[2][BB * GH];  // ping-pong, 64 KB
  __shared__ int arrive;
  const int tid = threadIdx.x;
  const int wave = tid >> 6, lane = tid & 63;
  const int j = blockIdx.x * 8 + wave;

  float wgr[32], wgz[32], wgn[32];
  {
    const float* pr = w_hh + (size_t)j * GH;
    const float* pz = w_hh + (size_t)(GH + j) * GH;
    const float* pn = w_hh + (size_t)(2 * GH + j) * GH;
#pragma unroll
    for (int c = 0; c < 32; ++c) {
      int k = c * 64 + lane;
      wgr[c] = pr[k]; wgz[c] = pz[k]; wgn[c] = pn[k];
    }
  }
  // stage hn into buffer 0 (swizzled slots)
#pragma unroll
  for (int i = 0; i < 4; ++i) {
    int k = tid + i * 512;
    float4 v;
    v.x = hn[0 * GH + k]; v.y = hn[1 * GH + k];
    v.z = hn[2 * GH + k]; v.w = hn[3 * GH + k];
    int slot = (k & ~63) | ((k & 3) << 4) | ((k >> 2) & 15);
    *(float4*)(&hsm[0][slot * 4]) = v;
  }
  if (tid == 0) arrive = 0;
  __syncthreads();

  const int rdo = (((lane & 3) << 4) | (lane >> 2)) * 4;       // read offset (floats)
  const int hpo = (((j & ~63) | ((j & 3) << 4) | ((j >> 2) & 15))) * 4;  // slot of own col
  const int wsb = ((((tid >> 4) << 6) | (tid & 15))) * 4;      // restage base (floats)

  for (int s = 0; s < SS; ++s) {
    const float* cur = hsm[s & 1];
    float* nxt = hsm[(s + 1) & 1];

    float xr = 0.f, xz = 0.f, xn_ = 0.f;
    if (lane < BB) {
      const float* xrow = xi + ((size_t)(lane * SS + s)) * G3;
      xr  = xrow[j];
      xz  = xrow[GH + j];
      xn_ = xrow[2 * GH + j];
    }

    float ar[BB] = {}, az[BB] = {}, an[BB] = {};
#pragma unroll
    for (int c = 0; c < 32; ++c) {
      float4 h4 = *(const float4*)(cur + c * 256 + rdo);  // = h[0..3][c*64+lane]
      float w_r = wgr[c], w_z = wgz[c], w_n = wgn[c];
      ar[0] = fmaf(w_r, h4.x, ar[0]); az[0] = fmaf(w_z, h4.x, az[0]); an[0] = fmaf(w_n, h4.x, an[0]);
      ar[1] = fmaf(w_r, h4.y, ar[1]); az[1] = fmaf(w_z, h4.y, az[1]); an[1] = fmaf(w_n, h4.y, an[1]);
      ar[2] = fmaf(w_r, h4.z, ar[2]); az[2] = fmaf(w_z, h4.z, az[2]); an[2] = fmaf(w_n, h4.z, an[2]);
      ar[3] = fmaf(w_r, h4.w, ar[3]); az[3] = fmaf(w_z, h4.w, az[3]); an[3] = fmaf(w_n, h4.w, an[3]);
    }
#pragma unroll
    for (int b = 0; b < BB; ++b) { ar[b] = wred64(ar[b]); az[b] = wred64(az[b]); an[b] = wred64(an[b]); }

    if (lane < BB) {
      const int b = lane;
      float r = 1.0f / (1.0f + expf(-(xr + ar[b])));
      float z = 1.0f / (1.0f + expf(-(xz + az[b])));
      float n = tanhf(xn_ + r * an[b]);
      float hp = cur[hpo + b];
      float hv = (1.0f - z) * n + z * hp;
      // write-through store (agent scope): visible at L3, no fence needed
      __hip_atomic_store(hsx + (((size_t)s * 256 + blockIdx.x) * BB + b) * 8 + (j & 7),
                         hv, __ATOMIC_RELAXED, __HIP_MEMORY_SCOPE_AGENT);
    }

    if (s + 1 < SS) {
      // per-wave publish: drain own stores, arrive; 8th arriver sets flag
      asm volatile("s_waitcnt vmcnt(0)" ::: "memory");
      if (lane == 0) {
        int old = atomicAdd(&arrive, 1);
        if (old == 8 * (s + 1) - 1)
          __hip_atomic_store(&flags[blockIdx.x * FPAD], s + 1,
                             __ATOMIC_RELAXED, __HIP_MEMORY_SCOPE_AGENT);
      }
      // consumer: cols 4t..4t+3 live in producer block t>>1's 128B line
      const int p = tid >> 1;
      const int c4 = (tid & 1) * 4;
      const int want = s + 1;
      while (__hip_atomic_load(&flags[p * FPAD], __ATOMIC_RELAXED,
                               __HIP_MEMORY_SCOPE_AGENT) < want)
        __builtin_amdgcn_s_sleep(1);
      const float* line = hsx + ((size_t)s * 256 + p) * 32 + c4;
      float4 v0 = *(const float4*)(line + 0 * 8);
      float4 v1 = *(const float4*)(line + 1 * 8);
      float4 v2 = *(const float4*)(line + 2 * 8);
      float4 v3 = *(const float4*)(line + 3 * 8);
      // restage into the OTHER buffer at swizzled slots (bank-minimal)
      *(float4*)(nxt + wsb +   0) = float4{v0.x, v1.x, v2.x, v3.x};
      *(float4*)(nxt + wsb +  64) = float4{v0.y, v1.y, v2.y, v3.y};
      *(float4*)(nxt + wsb + 128) = float4{v0.z, v1.z, v2.z, v3.z};
      *(float4*)(nxt + wsb + 192) = float4{v0.w, v1.w, v2.w, v3.w};
      __syncthreads();  // restage complete before next step's reads
    }
  }
}

// ---------------- per-token: normalize, gram/speciality, cosine --------------
__device__ inline float red16(float v) {
#pragma unroll
  for (int o = 8; o; o >>= 1) v += __shfl_xor(v, o);
  return v;
}

__global__ __launch_bounds__(256) void token_kernel(const float* __restrict__ hsx,
                                                    const float* __restrict__ expr,
                                                    float* __restrict__ cos_out,
                                                    float* __restrict__ sp_accum) {
  __shared__ float routn[EE * 132];
  __shared__ float rowc[EE];
  const int t = blockIdx.x;           // b*S + s
  const int b = t / SS, s = t % SS;
  const int tid = threadIdx.x;
  const int e = tid >> 4, sub = tid & 15;

  // k = e*128 + sub*8 + i  ->  hsx[(s*256 + (k>>3))*32 + b*8 + (k&7)]
  const float* rrow = hsx + ((size_t)s * 256 + e * 16 + sub) * 32 + b * 8;
  float rv[8];
  *(float4*)(rv)     = *(const float4*)(rrow);
  *(float4*)(rv + 4) = *(const float4*)(rrow + 4);
  float ss = 0.f;
#pragma unroll
  for (int i = 0; i < 8; ++i) ss += rv[i] * rv[i];
  ss = red16(ss);
  float inv = 1.0f / fmaxf(sqrtf(ss), 1e-12f);
#pragma unroll
  for (int i = 0; i < 8; ++i) {
    rv[i] *= inv;
    routn[e * 132 + sub * 8 + i] = rv[i];
  }

  const float* erow = expr + (size_t)t * GH + e * DD + sub * 8;
  float en2 = 0.f, dot = 0.f;
#pragma unroll
  for (int i = 0; i < 8; ++i) {
    float ev = erow[i];
    en2 += ev * ev;
    dot += ev * rv[i];
  }
  en2 = red16(en2);
  dot = red16(dot);
  if (sub == 0) {
    float cosv = dot / fmaxf(sqrtf(en2), 1e-8f);
    cos_out[t * EE + e] = 1.0f - cosv;
  }
  __syncthreads();

  const int f = sub;
  float g = 0.f;
#pragma unroll
  for (int d = 0; d < DD; ++d)
    g = fmaf(routn[e * 132 + d], routn[f * 132 + d], g);
  float diff = g - ((e == f) ? 1.0f : 0.0f);
  float rowsum = red16(diff * diff);
  if (f == 0) {
    float nrm = fmaxf(sqrtf(rowsum), 1e-12f);
    rowc[e] = rowsum / (nrm * nrm);
  }
  __syncthreads();
  if (tid == 0) {
    float tok = 0.f;
#pragma unroll
    for (int i = 0; i < EE; ++i) tok += rowc[i];
    atomicAdd(sp_accum, tok);
  }
}

// ---------------- final: top-2 + softmax + EMA adjust + hn copy + scalars ----
__global__ __launch_bounds__(256) void final_kernel(const float* __restrict__ hsx,
                                                    const float* __restrict__ cos_out,
                                                    const float* __restrict__ ema,
                                                    const float* __restrict__ accum,
                                                    float* __restrict__ out_mult,
                                                    float* __restrict__ out_sel,
                                                    float* __restrict__ out_hn,
                                                    float* __restrict__ out_sp,
                                                    float* __restrict__ out_el) {
  const int gtid = blockIdx.x * 256 + threadIdx.x;
  if (gtid < BB * GH) {
    int b = gtid / GH, k = gtid % GH;
    out_hn[gtid] = hsx[((size_t)(SS - 1) * 256 + (k >> 3)) * 32 + b * 8 + (k & 7)];
  }
  if (gtid < NTOK) {
    float sp = accum[0] / (float)NTOK;
    float scale = 1.0f + sp;
    float dv[EE];
#pragma unroll
    for (int e = 0; e < EE; ++e) dv[e] = cos_out[gtid * EE + e] * scale;
    int i0 = 0; float v0 = dv[0];
#pragma unroll
    for (int e = 1; e < EE; ++e) { if (dv[e] > v0) { v0 = dv[e]; i0 = e; } }
    int i1 = -1; float v1 = -1e30f;
#pragma unroll
    for (int e = 0; e < EE; ++e) { if (e != i0 && dv[e] > v1) { v1 = dv[e]; i1 = e; } }
    float ex = expf(v1 - v0);
    float den = 1.0f + ex;
    float m0 = 1.0f / den, m1 = ex / den;
    float total = 0.f;
#pragma unroll
    for (int e = 0; e < EE; ++e) total += ema[e];
    float a0 = 0.f, a1 = 0.f;
    if (total > 0.f) {
      float invt = 1.0f / fmaxf(total, 1e-12f);
      a0 = ema[i0] * invt * 0.01f * (float)EE;
      a1 = ema[i1] * invt * 0.01f * (float)EE;
    }
    out_mult[gtid * 2 + 0] = m0 - a0;
    out_mult[gtid * 2 + 1] = m1 - a1;
    out_sel[gtid * 2 + 0] = (float)i0;
    out_sel[gtid * 2 + 1] = (float)i1;
  }
  if (gtid == 0) {
    out_sp[0] = accum[0] / (float)NTOK;
    out_el[0] = accum[1] / (float)(GH * GH);
  }
}

extern "C" void kernel_launch(void* const* d_in, const int* in_sizes, int n_in,
                              void* d_out, int out_size, void* d_ws, size_t ws_size,
                              hipStream_t stream) {
  const float* x      = (const float*)d_in[0];  // [B,S,H]
  const float* hn     = (const float*)d_in[1];  // [1,B,GH]
  const float* w_ih   = (const float*)d_in[2];  // [3GH,H]
  const float* w_hh   = (const float*)d_in[3];  // [3GH,GH]
  const float* w_expr = (const float*)d_in[4];  // [H,GH]
  const float* ema    = (const float*)d_in[5];  // [E]
  float* out = (float*)d_out;

  float* out_mult = out;                 // 4096
  float* out_sel  = out + 4096;          // 4096
  float* out_expr = out + 8192;          // 4194304
  float* out_hn   = out + 4202496;       // 8192
  float* out_sp   = out + 4210688;       // 1
  float* out_cos  = out + 4210689;       // 32768
  float* out_el   = out + 4243457;       // 1

  float* ws = (float*)d_ws;
  float* xi    = ws;                      // 12,582,912 floats
  float* hsx   = ws + 12582912;           // [S][256][4][8] = 4,194,304 floats
  float* accum = ws + 16777216;           // [0]=sp_sum, [1]=el_sum
  int*   flags = (int*)(ws + 16777220);   // 256*FPAD ints
  // bf16 split arrays (guarded by ws_size)
  unsigned short* xh  = (unsigned short*)(ws + 16785920);  // 4.2M shorts
  unsigned short* xl  = (unsigned short*)(ws + 18883072);
  unsigned short* wth = (unsigned short*)(ws + 20980224);  // w_exprT hi
  unsigned short* wtl = (unsigned short*)(ws + 23077376);
  const size_t need_bytes = (size_t)25174528 * 4;
  const bool bf16path = ws_size >= need_bytes;

  hipMemsetAsync(accum, 0, (4 + 256 * FPAD) * sizeof(float), stream);

  // xi = x @ w_ih^T (fp32 — feeds chaotic recurrence)
  gemm_abt<<<dim3(G3 / 128, NTOK / 128), 256, 0, stream>>>(x, w_ih, xi, NTOK, G3, HH);

  if (bf16path) {
    split_mat<<<4096, 256, 0, stream>>>(x, xh, xl, NTOK * HH);
    transpose_split<<<dim3(GH / 64, HH / 64), 256, 0, stream>>>(w_expr, wth, wtl);
    // expression_logits = x @ w_expr = x * (w_exprT)^T
    gemm_abt_bf16<<<dim3(GH / 128, NTOK / 128), 256, 0, stream>>>(
        xh, xl, wth, wtl, out_expr, NTOK, GH, HH);
    // expression loss: (w_exprT * w_exprT^T - I)^2 mean
    ata_bf16<<<dim3(GH / 128, GH / 128), 256, 0, stream>>>(wth, wtl, accum + 1, GH, HH);
  } else {
    gemm_ab<<<dim3(GH / 128, NTOK / 128), 256, 0, stream>>>(x, w_expr, out_expr, NTOK, GH, HH);
    ata_loss<<<dim3(GH / 128, GH / 128), 256, 0, stream>>>(w_expr, accum + 1, GH, HH);
  }

  // GRU recurrence: persistent cooperative kernel, line-granular flags
  {
    void* args[] = {(void*)&xi, (void*)&w_hh, (void*)&hn, (void*)&hsx, (void*)&flags};
    hipLaunchCooperativeKernel((void*)gru_persistent, dim3(256), dim3(512),
                               args, 0, stream);
  }

  token_kernel<<<NTOK, 256, 0, stream>>>(hsx, out_expr, out_cos, accum);

  final_kernel<<<(BB * GH + 255) / 256, 256, 0, stream>>>(hsx, out_cos, ema, accum,
                                                          out_mult, out_sel, out_hn,
                                                          out_sp, out_el);
}

// Round 3
// 3882.974 us; speedup vs baseline: 1.2526x; 1.2526x over previous
//
#include <hip/hip_runtime.h>
#include <hip/hip_bf16.h>
#include <math.h>

// Problem constants (from reference setup_inputs)
#define BB 4
#define SS 512
#define HH 2048
#define EE 16
#define DD 128
#define GH 2048           // E*D
#define G3 6144           // 3*GH
#define NTOK 2048         // B*S

#define LSTR 132          // LDS leading-dim pad for 128-wide fp32 tiles
#define FPAD 32           // flag padding: one flag per 128 B
#define KS 40             // bf16 LDS row stride in shorts (32 + 8 pad)

typedef __attribute__((ext_vector_type(8))) short short8;   // 8 bf16 = 4 VGPR
typedef __attribute__((ext_vector_type(4))) float f32x4;    // MFMA C/D

// ---------------- GEMM 1 (fp32): C[M,N] = A[M,K] * B[N,K]^T ------------------
// xi = x @ w_ih^T. Kept fp32: xi feeds the chaotic GRU recurrence (absmax
// 0.0156 from fp32-level seeds implies ~1e4 amplification; bf16 here would
// blow the threshold). Tile 128x128, BK=8, 8x8/thread.
__global__ __launch_bounds__(256) void gemm_abt(const float* __restrict__ A,
                                                const float* __restrict__ B,
                                                float* __restrict__ C,
                                                int M, int N, int K) {
  __shared__ float As[8][LSTR];
  __shared__ float Bs[8][LSTR];
  const int bm = blockIdx.y * 128, bn = blockIdx.x * 128;
  const int tid = threadIdx.x;
  const int lm = tid >> 1;
  const int kh = (tid & 1) * 4;
  const int tx = tid & 15, ty = tid >> 4;
  float acc[8][8] = {};
  const float* Arow = A + (size_t)(bm + lm) * K + kh;
  const float* Brow = B + (size_t)(bn + lm) * K + kh;
  for (int k0 = 0; k0 < K; k0 += 8) {
    float4 av = *(const float4*)(Arow + k0);
    float4 bv = *(const float4*)(Brow + k0);
    As[kh + 0][lm] = av.x; As[kh + 1][lm] = av.y; As[kh + 2][lm] = av.z; As[kh + 3][lm] = av.w;
    Bs[kh + 0][lm] = bv.x; Bs[kh + 1][lm] = bv.y; Bs[kh + 2][lm] = bv.z; Bs[kh + 3][lm] = bv.w;
    __syncthreads();
#pragma unroll
    for (int kk = 0; kk < 8; ++kk) {
      float a8[8], b8[8];
      *(float4*)(a8)     = *(const float4*)(&As[kk][ty * 8]);
      *(float4*)(a8 + 4) = *(const float4*)(&As[kk][ty * 8 + 4]);
      *(float4*)(b8)     = *(const float4*)(&Bs[kk][tx * 8]);
      *(float4*)(b8 + 4) = *(const float4*)(&Bs[kk][tx * 8 + 4]);
#pragma unroll
      for (int i = 0; i < 8; ++i)
#pragma unroll
        for (int j = 0; j < 8; ++j) acc[i][j] = fmaf(a8[i], b8[j], acc[i][j]);
    }
    __syncthreads();
  }
#pragma unroll
  for (int i = 0; i < 8; ++i) {
    float4 v0 = {acc[i][0], acc[i][1], acc[i][2], acc[i][3]};
    float4 v1 = {acc[i][4], acc[i][5], acc[i][6], acc[i][7]};
    float* crow = C + (size_t)(bm + ty * 8 + i) * N + bn + tx * 8;
    *(float4*)(crow)     = v0;
    *(float4*)(crow + 4) = v1;
  }
}

// ---------------- fp32 fallbacks (used only if ws too small) -----------------
__global__ __launch_bounds__(256) void gemm_ab(const float* __restrict__ A,
                                               const float* __restrict__ B,
                                               float* __restrict__ C,
                                               int M, int N, int K) {
  __shared__ float As[8][LSTR];
  __shared__ float Bs[8][LSTR];
  const int bm = blockIdx.y * 128, bn = blockIdx.x * 128;
  const int tid = threadIdx.x;
  const int lm = tid >> 1;
  const int kh = (tid & 1) * 4;
  const int bk = tid >> 5;
  const int bn4 = (tid & 31) * 4;
  const int tx = tid & 15, ty = tid >> 4;
  float acc[8][8] = {};
  const float* Arow = A + (size_t)(bm + lm) * K + kh;
  for (int k0 = 0; k0 < K; k0 += 8) {
    float4 av = *(const float4*)(Arow + k0);
    float4 bv = *(const float4*)(B + (size_t)(k0 + bk) * N + bn + bn4);
    As[kh + 0][lm] = av.x; As[kh + 1][lm] = av.y; As[kh + 2][lm] = av.z; As[kh + 3][lm] = av.w;
    *(float4*)(&Bs[bk][bn4]) = bv;
    __syncthreads();
#pragma unroll
    for (int kk = 0; kk < 8; ++kk) {
      float a8[8], b8[8];
      *(float4*)(a8)     = *(const float4*)(&As[kk][ty * 8]);
      *(float4*)(a8 + 4) = *(const float4*)(&As[kk][ty * 8 + 4]);
      *(float4*)(b8)     = *(const float4*)(&Bs[kk][tx * 8]);
      *(float4*)(b8 + 4) = *(const float4*)(&Bs[kk][tx * 8 + 4]);
#pragma unroll
      for (int i = 0; i < 8; ++i)
#pragma unroll
        for (int j = 0; j < 8; ++j) acc[i][j] = fmaf(a8[i], b8[j], acc[i][j]);
    }
    __syncthreads();
  }
#pragma unroll
  for (int i = 0; i < 8; ++i) {
    float4 v0 = {acc[i][0], acc[i][1], acc[i][2], acc[i][3]};
    float4 v1 = {acc[i][4], acc[i][5], acc[i][6], acc[i][7]};
    float* crow = C + (size_t)(bm + ty * 8 + i) * N + bn + tx * 8;
    *(float4*)(crow)     = v0;
    *(float4*)(crow + 4) = v1;
  }
}

__global__ __launch_bounds__(256) void ata_loss(const float* __restrict__ A,
                                                float* __restrict__ el_accum,
                                                int N, int K) {
  __shared__ float As[8][LSTR];
  __shared__ float Bs[8][LSTR];
  __shared__ float red[256];
  const int bi = blockIdx.y * 128, bj = blockIdx.x * 128;
  const int tid = threadIdx.x;
  const int bk = tid >> 5;
  const int bn4 = (tid & 31) * 4;
  const int tx = tid & 15, ty = tid >> 4;
  float acc[8][8] = {};
  for (int k0 = 0; k0 < K; k0 += 8) {
    float4 av = *(const float4*)(A + (size_t)(k0 + bk) * N + bi + bn4);
    float4 bv = *(const float4*)(A + (size_t)(k0 + bk) * N + bj + bn4);
    *(float4*)(&As[bk][bn4]) = av;
    *(float4*)(&Bs[bk][bn4]) = bv;
    __syncthreads();
#pragma unroll
    for (int kk = 0; kk < 8; ++kk) {
      float a8[8], b8[8];
      *(float4*)(a8)     = *(const float4*)(&As[kk][ty * 8]);
      *(float4*)(a8 + 4) = *(const float4*)(&As[kk][ty * 8 + 4]);
      *(float4*)(b8)     = *(const float4*)(&Bs[kk][tx * 8]);
      *(float4*)(b8 + 4) = *(const float4*)(&Bs[kk][tx * 8 + 4]);
#pragma unroll
      for (int i = 0; i < 8; ++i)
#pragma unroll
        for (int j = 0; j < 8; ++j) acc[i][j] = fmaf(a8[i], b8[j], acc[i][j]);
    }
    __syncthreads();
  }
  float local = 0.f;
#pragma unroll
  for (int i = 0; i < 8; ++i) {
#pragma unroll
    for (int j = 0; j < 8; ++j) {
      int gi = bi + ty * 8 + i, gj = bj + tx * 8 + j;
      float d = acc[i][j] - ((gi == gj) ? 1.0f : 0.0f);
      local += d * d;
    }
  }
  red[tid] = local;
  __syncthreads();
  for (int s = 128; s > 0; s >>= 1) {
    if (tid < s) red[tid] += red[tid + s];
    __syncthreads();
  }
  if (tid == 0) atomicAdd(el_accum, red[0]);
}

// ---------------- split-bf16 helpers -----------------------------------------
__device__ inline void bf16_split(float v, unsigned short& hi, unsigned short& lo) {
  unsigned u = __float_as_uint(v);
  unsigned r = u + 0x7FFFu + ((u >> 16) & 1u);   // RTN-even to bf16
  hi = (unsigned short)(r >> 16);
  float rem = v - __uint_as_float((unsigned)hi << 16);  // exact (Sterbenz)
  lo = (unsigned short)(__float_as_uint(rem) >> 16);    // truncate remainder
}

__global__ __launch_bounds__(256) void split_mat(const float* __restrict__ A,
                                                 unsigned short* __restrict__ Hh,
                                                 unsigned short* __restrict__ Hl,
                                                 int n) {
  int i = blockIdx.x * 256 + threadIdx.x;
  int stride = gridDim.x * 256;
  for (; i < n; i += stride) {
    unsigned short hi, lo;
    bf16_split(A[i], hi, lo);
    Hh[i] = hi; Hl[i] = lo;
  }
}

// w_expr [H][GH] -> transposed split T[GH][H] (hi/lo bf16)
__global__ __launch_bounds__(256) void transpose_split(const float* __restrict__ A,
                                                       unsigned short* __restrict__ Th,
                                                       unsigned short* __restrict__ Tl) {
  __shared__ float tile[64][65];
  const int bx = blockIdx.x * 64, by = blockIdx.y * 64;  // bx: n, by: k
  const int tx = threadIdx.x & 63, ty = threadIdx.x >> 6;
#pragma unroll
  for (int i = 0; i < 16; ++i) {
    int r = ty + i * 4;
    tile[r][tx] = A[(size_t)(by + r) * GH + bx + tx];
  }
  __syncthreads();
#pragma unroll
  for (int i = 0; i < 16; ++i) {
    int r = ty + i * 4;                 // output row n = bx + r; col k = by + tx
    unsigned short hi, lo;
    bf16_split(tile[tx][r], hi, lo);
    Th[(size_t)(bx + r) * HH + by + tx] = hi;
    Tl[(size_t)(bx + r) * HH + by + tx] = lo;
  }
}

// ---------------- split-bf16 MFMA GEMM: C[M,N] = A[M,K]*B[N,K]^T -------------
// A,B given as bf16 (hi,lo); acc = Ah*Bh + Ah*Bl + Al*Bh (drop Al*Bl ~2^-18).
// 128x128 tile, BK=32 (one 16x16x32 MFMA k-step), 4 waves x 64x64 quadrant,
// padded LDS stride (KS=40 shorts) -> <=2-way bank conflicts (free per m136).
__global__ __launch_bounds__(256) void gemm_abt_bf16(
    const unsigned short* __restrict__ Ah, const unsigned short* __restrict__ Al,
    const unsigned short* __restrict__ Bh, const unsigned short* __restrict__ Bl,
    float* __restrict__ C, int M, int N, int K) {
  __shared__ unsigned short Ahs[128 * KS], Als[128 * KS];
  __shared__ unsigned short Bhs[128 * KS], Bls[128 * KS];
  const int tid = threadIdx.x;
  const int wv = tid >> 6, lane = tid & 63;
  const int qr = wv >> 1, qc = wv & 1;
  const int m16 = lane & 15, q = lane >> 4;
  const int bm = blockIdx.y * 128, bn = blockIdx.x * 128;
  const int sr = tid >> 1, sh = (tid & 1) * 16;   // staging: row, k-half
  f32x4 zero = {0.f, 0.f, 0.f, 0.f};
  f32x4 acc[4][4];
#pragma unroll
  for (int i = 0; i < 4; ++i)
#pragma unroll
    for (int j = 0; j < 4; ++j) acc[i][j] = zero;

  for (int k0 = 0; k0 < K; k0 += 32) {
    const size_t ga = (size_t)(bm + sr) * K + k0 + sh;
    const size_t gb = (size_t)(bn + sr) * K + k0 + sh;
    short8 a0 = *(const short8*)(Ah + ga);
    short8 a1 = *(const short8*)(Ah + ga + 8);
    short8 l0 = *(const short8*)(Al + ga);
    short8 l1 = *(const short8*)(Al + ga + 8);
    short8 b0 = *(const short8*)(Bh + gb);
    short8 b1 = *(const short8*)(Bh + gb + 8);
    short8 m0 = *(const short8*)(Bl + gb);
    short8 m1 = *(const short8*)(Bl + gb + 8);
    __syncthreads();   // previous iter's frag reads complete
    *(short8*)&Ahs[sr * KS + sh]     = a0;
    *(short8*)&Ahs[sr * KS + sh + 8] = a1;
    *(short8*)&Als[sr * KS + sh]     = l0;
    *(short8*)&Als[sr * KS + sh + 8] = l1;
    *(short8*)&Bhs[sr * KS + sh]     = b0;
    *(short8*)&Bhs[sr * KS + sh + 8] = b1;
    *(short8*)&Bls[sr * KS + sh]     = m0;
    *(short8*)&Bls[sr * KS + sh + 8] = m1;
    __syncthreads();
    short8 afh[4], afl[4], bfh[4], bfl[4];
#pragma unroll
    for (int t = 0; t < 4; ++t) {
      const int raddr = (qr * 64 + t * 16 + m16) * KS + q * 8;
      const int caddr = (qc * 64 + t * 16 + m16) * KS + q * 8;
      afh[t] = *(const short8*)&Ahs[raddr];
      afl[t] = *(const short8*)&Als[raddr];
      bfh[t] = *(const short8*)&Bhs[caddr];
      bfl[t] = *(const short8*)&Bls[caddr];
    }
#pragma unroll
    for (int tm = 0; tm < 4; ++tm)
#pragma unroll
      for (int tn = 0; tn < 4; ++tn) {
        acc[tm][tn] = __builtin_amdgcn_mfma_f32_16x16x32_bf16(afh[tm], bfh[tn], acc[tm][tn], 0, 0, 0);
        acc[tm][tn] = __builtin_amdgcn_mfma_f32_16x16x32_bf16(afh[tm], bfl[tn], acc[tm][tn], 0, 0, 0);
        acc[tm][tn] = __builtin_amdgcn_mfma_f32_16x16x32_bf16(afl[tm], bfh[tn], acc[tm][tn], 0, 0, 0);
      }
  }
  // C/D layout: col = lane&15, row = (lane>>4)*4 + reg  [m89-verified]
#pragma unroll
  for (int tm = 0; tm < 4; ++tm)
#pragma unroll
    for (int tn = 0; tn < 4; ++tn)
#pragma unroll
      for (int r = 0; r < 4; ++r)
        C[(size_t)(bm + qr * 64 + tm * 16 + q * 4 + r) * N +
          bn + qc * 64 + tn * 16 + m16] = acc[tm][tn][r];
}

// same mainloop, A=B=w_exprT; epilogue reduces (g - I)^2 instead of writing C
__global__ __launch_bounds__(256) void ata_bf16(
    const unsigned short* __restrict__ Th, const unsigned short* __restrict__ Tl,
    float* __restrict__ el_accum, int N, int K) {
  __shared__ unsigned short Ahs[128 * KS], Als[128 * KS];
  __shared__ unsigned short Bhs[128 * KS], Bls[128 * KS];
  __shared__ float red[256];
  const int tid = threadIdx.x;
  const int wv = tid >> 6, lane = tid & 63;
  const int qr = wv >> 1, qc = wv & 1;
  const int m16 = lane & 15, q = lane >> 4;
  const int bi = blockIdx.y * 128, bj = blockIdx.x * 128;
  const int sr = tid >> 1, sh = (tid & 1) * 16;
  f32x4 zero = {0.f, 0.f, 0.f, 0.f};
  f32x4 acc[4][4];
#pragma unroll
  for (int i = 0; i < 4; ++i)
#pragma unroll
    for (int j = 0; j < 4; ++j) acc[i][j] = zero;

  for (int k0 = 0; k0 < K; k0 += 32) {
    const size_t ga = (size_t)(bi + sr) * K + k0 + sh;
    const size_t gb = (size_t)(bj + sr) * K + k0 + sh;
    short8 a0 = *(const short8*)(Th + ga);
    short8 a1 = *(const short8*)(Th + ga + 8);
    short8 l0 = *(const short8*)(Tl + ga);
    short8 l1 = *(const short8*)(Tl + ga + 8);
    short8 b0 = *(const short8*)(Th + gb);
    short8 b1 = *(const short8*)(Th + gb + 8);
    short8 m0 = *(const short8*)(Tl + gb);
    short8 m1 = *(const short8*)(Tl + gb + 8);
    __syncthreads();
    *(short8*)&Ahs[sr * KS + sh]     = a0;
    *(short8*)&Ahs[sr * KS + sh + 8] = a1;
    *(short8*)&Als[sr * KS + sh]     = l0;
    *(short8*)&Als[sr * KS + sh + 8] = l1;
    *(short8*)&Bhs[sr * KS + sh]     = b0;
    *(short8*)&Bhs[sr * KS + sh + 8] = b1;
    *(short8*)&Bls[sr * KS + sh]     = m0;
    *(short8*)&Bls[sr * KS + sh + 8] = m1;
    __syncthreads();
    short8 afh[4], afl[4], bfh[4], bfl[4];
#pragma unroll
    for (int t = 0; t < 4; ++t) {
      const int raddr = (qr * 64 + t * 16 + m16) * KS + q * 8;
      const int caddr = (qc * 64 + t * 16 + m16) * KS + q * 8;
      afh[t] = *(const short8*)&Ahs[raddr];
      afl[t] = *(const short8*)&Als[raddr];
      bfh[t] = *(const short8*)&Bhs[caddr];
      bfl[t] = *(const short8*)&Bls[caddr];
    }
#pragma unroll
    for (int tm = 0; tm < 4; ++tm)
#pragma unroll
      for (int tn = 0; tn < 4; ++tn) {
        acc[tm][tn] = __builtin_amdgcn_mfma_f32_16x16x32_bf16(afh[tm], bfh[tn], acc[tm][tn], 0, 0, 0);
        acc[tm][tn] = __builtin_amdgcn_mfma_f32_16x16x32_bf16(afh[tm], bfl[tn], acc[tm][tn], 0, 0, 0);
        acc[tm][tn] = __builtin_amdgcn_mfma_f32_16x16x32_bf16(afl[tm], bfh[tn], acc[tm][tn], 0, 0, 0);
      }
  }
  float local = 0.f;
#pragma unroll
  for (int tm = 0; tm < 4; ++tm)
#pragma unroll
    for (int tn = 0; tn < 4; ++tn)
#pragma unroll
      for (int r = 0; r < 4; ++r) {
        int gi = bi + qr * 64 + tm * 16 + q * 4 + r;
        int gj = bj + qc * 64 + tn * 16 + m16;
        float d = acc[tm][tn][r] - ((gi == gj) ? 1.0f : 0.0f);
        local += d * d;
      }
  red[tid] = local;
  __syncthreads();
  for (int s = 128; s > 0; s >>= 1) {
    if (tid < s) red[tid] += red[tid + s];
    __syncthreads();
  }
  if (tid == 0) atomicAdd(el_accum, red[0]);
}

// ---------------- persistent GRU: line-granular flag dataflow ----------------
// Wave reduction: 4 DPP row_ror stages (VALU pipe) + 2 shuffles for the
// cross-row halves. Moves 48 of 72 per-wave reduction ops off the contended
// LDS pipe onto the ~21%-busy VALU. DPP ctrl must be compile-time constant.
template <int CTRL>
__device__ inline float dpp_add(float v) {
  int t = __builtin_amdgcn_update_dpp(0, __float_as_int(v), CTRL, 0xf, 0xf, false);
  return v + __int_as_float(t);
}
__device__ inline float wred64(float v) {
  v = dpp_add<0x121>(v);   // row_ror:1
  v = dpp_add<0x122>(v);   // row_ror:2
  v = dpp_add<0x124>(v);   // row_ror:4
  v = dpp_add<0x128>(v);   // row_ror:8  -> every lane has its 16-row sum
  v += __shfl_xor(v, 16);
  v += __shfl_xor(v, 32);
  return v;
}

// hsm layout (R2): column k's float4 {h[0..3][k]} lives at 16B-slot
//   f(k) = k ^ ((k>>3)&3)    (XOR bits 4,3 into bits 1,0; bijective shear)
// Conflict proof (slot mod 8 = bank-quad):
//   READ  (lane l, iter c): k=c*64+l varies k2k1k0 -> f_low=(k2,k1^k4,k0^k3)
//         bijective over the 8-lane group -> conflict-free (as before).
//   WRITE (restage instr i, thread t): k=4t+i varies k4k3k2 (fixed k1k0=i)
//         -> f_low=(k2, i1^k4, i0^k3) bijective over the 8-lane group
//         -> conflict-free (old linear layout was 4-way here: the 1.0e8
//            SQ_LDS_BANK_CONFLICT of the 3157us baseline).
// R1's sigma swizzle fixed writes but made READS 4-way (4.0e8 conflicts,
// +840us) — reverted. Publish protocol reverted to the measured-good R0
// form: store -> __syncthreads (vmcnt drain) -> tid0 flag -> poll ->
// restage -> __syncthreads. Single 32KB hsm buffer.
__global__ __launch_bounds__(512, 2) void gru_persistent(
    const float* __restrict__ xi,    // [B,S,3GH]
    const float* __restrict__ w_hh,  // [3GH,GH]
    const float* __restrict__ hn,    // [B,GH]
    float* __restrict__ hsx,         // [S][256][4][8]
    int* __restrict__ flags) {       // [256*FPAD], zeroed
  __shared__ __align__(16) float hsm[BB * GH];  // col k at slot f(k), 32 KB
  const int tid = threadIdx.x;
  const int wave = tid >> 6, lane = tid & 63;
  const int j = blockIdx.x * 8 + wave;

  float wgr[32], wgz[32], wgn[32];
  {
    const float* pr = w_hh + (size_t)j * GH;
    const float* pz = w_hh + (size_t)(GH + j) * GH;
    const float* pn = w_hh + (size_t)(2 * GH + j) * GH;
#pragma unroll
    for (int c = 0; c < 32; ++c) {
      int k = c * 64 + lane;
      wgr[c] = pr[k]; wgz[c] = pz[k]; wgn[c] = pn[k];
    }
  }
  // stage hn (swizzled slots; lanes consecutive k -> conflict-free)
#pragma unroll
  for (int i = 0; i < 4; ++i) {
    int k = tid + i * 512;
    float4 v;
    v.x = hn[0 * GH + k]; v.y = hn[1 * GH + k];
    v.z = hn[2 * GH + k]; v.w = hn[3 * GH + k];
    int slot = k ^ ((k >> 3) & 3);
    *(float4*)(&hsm[slot * 4]) = v;
  }
  __syncthreads();

  const int rdo = (lane ^ ((lane >> 3) & 3)) * 4;   // read offset (floats)
  const int hpo = (j ^ ((j >> 3) & 3)) * 4;         // slot of own col
  int wslot[4];                                     // restage slots (floats)
#pragma unroll
  for (int i = 0; i < 4; ++i) {
    int k = tid * 4 + i;
    wslot[i] = (k ^ ((k >> 3) & 3)) * 4;
  }

  for (int s = 0; s < SS; ++s) {
    float xr = 0.f, xz = 0.f, xn_ = 0.f;
    if (lane < BB) {
      const float* xrow = xi + ((size_t)(lane * SS + s)) * G3;
      xr  = xrow[j];
      xz  = xrow[GH + j];
      xn_ = xrow[2 * GH + j];
    }

    float ar[BB] = {}, az[BB] = {}, an[BB] = {};
#pragma unroll
    for (int c = 0; c < 32; ++c) {
      float4 h4 = *(const float4*)(&hsm[c * 256 + rdo]);  // = h[0..3][c*64+lane]
      float w_r = wgr[c], w_z = wgz[c], w_n = wgn[c];
      ar[0] = fmaf(w_r, h4.x, ar[0]); az[0] = fmaf(w_z, h4.x, az[0]); an[0] = fmaf(w_n, h4.x, an[0]);
      ar[1] = fmaf(w_r, h4.y, ar[1]); az[1] = fmaf(w_z, h4.y, az[1]); an[1] = fmaf(w_n, h4.y, an[1]);
      ar[2] = fmaf(w_r, h4.z, ar[2]); az[2] = fmaf(w_z, h4.z, az[2]); an[2] = fmaf(w_n, h4.z, an[2]);
      ar[3] = fmaf(w_r, h4.w, ar[3]); az[3] = fmaf(w_z, h4.w, az[3]); an[3] = fmaf(w_n, h4.w, an[3]);
    }
#pragma unroll
    for (int b = 0; b < BB; ++b) { ar[b] = wred64(ar[b]); az[b] = wred64(az[b]); an[b] = wred64(an[b]); }

    if (lane < BB) {
      const int b = lane;
      float r = 1.0f / (1.0f + expf(-(xr + ar[b])));
      float z = 1.0f / (1.0f + expf(-(xz + az[b])));
      float n = tanhf(xn_ + r * an[b]);
      float hp = hsm[hpo + b];
      float hv = (1.0f - z) * n + z * hp;
      // write-through store (agent scope): visible at L3, no fence needed
      __hip_atomic_store(hsx + (((size_t)s * 256 + blockIdx.x) * BB + b) * 8 + (j & 7),
                         hv, __ATOMIC_RELAXED, __HIP_MEMORY_SCOPE_AGENT);
    }

    if (s + 1 < SS) {
      __syncthreads();  // drains vmcnt: this block's h stores are at L3
      if (tid == 0)
        __hip_atomic_store(&flags[blockIdx.x * FPAD], s + 1,
                           __ATOMIC_RELAXED, __HIP_MEMORY_SCOPE_AGENT);
      // per-thread: cols 4t..4t+3 live in producer block t>>1's 128B line
      const int p = tid >> 1;
      const int c4 = (tid & 1) * 4;
      const int want = s + 1;
      while (__hip_atomic_load(&flags[p * FPAD], __ATOMIC_RELAXED,
                               __HIP_MEMORY_SCOPE_AGENT) < want)
        __builtin_amdgcn_s_sleep(1);
      const float* line = hsx + ((size_t)s * 256 + p) * 32 + c4;
      float4 v0 = *(const float4*)(line + 0 * 8);
      float4 v1 = *(const float4*)(line + 1 * 8);
      float4 v2 = *(const float4*)(line + 2 * 8);
      float4 v3 = *(const float4*)(line + 3 * 8);
      // restage at swizzled slots (bank-minimal per the f_low proof above)
      *(float4*)(&hsm[wslot[0]]) = float4{v0.x, v1.x, v2.x, v3.x};
      *(float4*)(&hsm[wslot[1]]) = float4{v0.y, v1.y, v2.y, v3.y};
      *(float4*)(&hsm[wslot[2]]) = float4{v0.z, v1.z, v2.z, v3.z};
      *(float4*)(&hsm[wslot[3]]) = float4{v0.w, v1.w, v2.w, v3.w};
      __syncthreads();  // hsm fully restaged before next dot
    }
  }
}

// ---------------- per-token: normalize, gram/speciality, cosine --------------
__device__ inline float red16(float v) {
#pragma unroll
  for (int o = 8; o; o >>= 1) v += __shfl_xor(v, o);
  return v;
}

__global__ __launch_bounds__(256) void token_kernel(const float* __restrict__ hsx,
                                                    const float* __restrict__ expr,
                                                    float* __restrict__ cos_out,
                                                    float* __restrict__ sp_accum) {
  __shared__ float routn[EE * 132];
  __shared__ float rowc[EE];
  const int t = blockIdx.x;           // b*S + s
  const int b = t / SS, s = t % SS;
  const int tid = threadIdx.x;
  const int e = tid >> 4, sub = tid & 15;

  // k = e*128 + sub*8 + i  ->  hsx[(s*256 + (k>>3))*32 + b*8 + (k&7)]
  const float* rrow = hsx + ((size_t)s * 256 + e * 16 + sub) * 32 + b * 8;
  float rv[8];
  *(float4*)(rv)     = *(const float4*)(rrow);
  *(float4*)(rv + 4) = *(const float4*)(rrow + 4);
  float ss = 0.f;
#pragma unroll
  for (int i = 0; i < 8; ++i) ss += rv[i] * rv[i];
  ss = red16(ss);
  float inv = 1.0f / fmaxf(sqrtf(ss), 1e-12f);
#pragma unroll
  for (int i = 0; i < 8; ++i) {
    rv[i] *= inv;
    routn[e * 132 + sub * 8 + i] = rv[i];
  }

  const float* erow = expr + (size_t)t * GH + e * DD + sub * 8;
  float en2 = 0.f, dot = 0.f;
#pragma unroll
  for (int i = 0; i < 8; ++i) {
    float ev = erow[i];
    en2 += ev * ev;
    dot += ev * rv[i];
  }
  en2 = red16(en2);
  dot = red16(dot);
  if (sub == 0) {
    float cosv = dot / fmaxf(sqrtf(en2), 1e-8f);
    cos_out[t * EE + e] = 1.0f - cosv;
  }
  __syncthreads();

  const int f = sub;
  float g = 0.f;
#pragma unroll
  for (int d = 0; d < DD; ++d)
    g = fmaf(routn[e * 132 + d], routn[f * 132 + d], g);
  float diff = g - ((e == f) ? 1.0f : 0.0f);
  float rowsum = red16(diff * diff);
  if (f == 0) {
    float nrm = fmaxf(sqrtf(rowsum), 1e-12f);
    rowc[e] = rowsum / (nrm * nrm);
  }
  __syncthreads();
  if (tid == 0) {
    float tok = 0.f;
#pragma unroll
    for (int i = 0; i < EE; ++i) tok += rowc[i];
    atomicAdd(sp_accum, tok);
  }
}

// ---------------- final: top-2 + softmax + EMA adjust + hn copy + scalars ----
__global__ __launch_bounds__(256) void final_kernel(const float* __restrict__ hsx,
                                                    const float* __restrict__ cos_out,
                                                    const float* __restrict__ ema,
                                                    const float* __restrict__ accum,
                                                    float* __restrict__ out_mult,
                                                    float* __restrict__ out_sel,
                                                    float* __restrict__ out_hn,
                                                    float* __restrict__ out_sp,
                                                    float* __restrict__ out_el) {
  const int gtid = blockIdx.x * 256 + threadIdx.x;
  if (gtid < BB * GH) {
    int b = gtid / GH, k = gtid % GH;
    out_hn[gtid] = hsx[((size_t)(SS - 1) * 256 + (k >> 3)) * 32 + b * 8 + (k & 7)];
  }
  if (gtid < NTOK) {
    float sp = accum[0] / (float)NTOK;
    float scale = 1.0f + sp;
    float dv[EE];
#pragma unroll
    for (int e = 0; e < EE; ++e) dv[e] = cos_out[gtid * EE + e] * scale;
    int i0 = 0; float v0 = dv[0];
#pragma unroll
    for (int e = 1; e < EE; ++e) { if (dv[e] > v0) { v0 = dv[e]; i0 = e; } }
    int i1 = -1; float v1 = -1e30f;
#pragma unroll
    for (int e = 0; e < EE; ++e) { if (e != i0 && dv[e] > v1) { v1 = dv[e]; i1 = e; } }
    float ex = expf(v1 - v0);
    float den = 1.0f + ex;
    float m0 = 1.0f / den, m1 = ex / den;
    float total = 0.f;
#pragma unroll
    for (int e = 0; e < EE; ++e) total += ema[e];
    float a0 = 0.f, a1 = 0.f;
    if (total > 0.f) {
      float invt = 1.0f / fmaxf(total, 1e-12f);
      a0 = ema[i0] * invt * 0.01f * (float)EE;
      a1 = ema[i1] * invt * 0.01f * (float)EE;
    }
    out_mult[gtid * 2 + 0] = m0 - a0;
    out_mult[gtid * 2 + 1] = m1 - a1;
    out_sel[gtid * 2 + 0] = (float)i0;
    out_sel[gtid * 2 + 1] = (float)i1;
  }
  if (gtid == 0) {
    out_sp[0] = accum[0] / (float)NTOK;
    out_el[0] = accum[1] / (float)(GH * GH);
  }
}

extern "C" void kernel_launch(void* const* d_in, const int* in_sizes, int n_in,
                              void* d_out, int out_size, void* d_ws, size_t ws_size,
                              hipStream_t stream) {
  const float* x      = (const float*)d_in[0];  // [B,S,H]
  const float* hn     = (const float*)d_in[1];  // [1,B,GH]
  const float* w_ih   = (const float*)d_in[2];  // [3GH,H]
  const float* w_hh   = (const float*)d_in[3];  // [3GH,GH]
  const float* w_expr = (const float*)d_in[4];  // [H,GH]
  const float* ema    = (const float*)d_in[5];  // [E]
  float* out = (float*)d_out;

  float* out_mult = out;                 // 4096
  float* out_sel  = out + 4096;          // 4096
  float* out_expr = out + 8192;          // 4194304
  float* out_hn   = out + 4202496;       // 8192
  float* out_sp   = out + 4210688;       // 1
  float* out_cos  = out + 4210689;       // 32768
  float* out_el   = out + 4243457;       // 1

  float* ws = (float*)d_ws;
  float* xi    = ws;                      // 12,582,912 floats
  float* hsx   = ws + 12582912;           // [S][256][4][8] = 4,194,304 floats
  float* accum = ws + 16777216;           // [0]=sp_sum, [1]=el_sum
  int*   flags = (int*)(ws + 16777220);   // 256*FPAD ints
  // bf16 split arrays (guarded by ws_size)
  unsigned short* xh  = (unsigned short*)(ws + 16785920);  // 4.2M shorts
  unsigned short* xl  = (unsigned short*)(ws + 18883072);
  unsigned short* wth = (unsigned short*)(ws + 20980224);  // w_exprT hi
  unsigned short* wtl = (unsigned short*)(ws + 23077376);
  const size_t need_bytes = (size_t)25174528 * 4;
  const bool bf16path = ws_size >= need_bytes;

  hipMemsetAsync(accum, 0, (4 + 256 * FPAD) * sizeof(float), stream);

  // xi = x @ w_ih^T (fp32 — feeds chaotic recurrence)
  gemm_abt<<<dim3(G3 / 128, NTOK / 128), 256, 0, stream>>>(x, w_ih, xi, NTOK, G3, HH);

  if (bf16path) {
    split_mat<<<4096, 256, 0, stream>>>(x, xh, xl, NTOK * HH);
    transpose_split<<<dim3(GH / 64, HH / 64), 256, 0, stream>>>(w_expr, wth, wtl);
    // expression_logits = x @ w_expr = x * (w_exprT)^T
    gemm_abt_bf16<<<dim3(GH / 128, NTOK / 128), 256, 0, stream>>>(
        xh, xl, wth, wtl, out_expr, NTOK, GH, HH);
    // expression loss: (w_exprT * w_exprT^T - I)^2 mean
    ata_bf16<<<dim3(GH / 128, GH / 128), 256, 0, stream>>>(wth, wtl, accum + 1, GH, HH);
  } else {
    gemm_ab<<<dim3(GH / 128, NTOK / 128), 256, 0, stream>>>(x, w_expr, out_expr, NTOK, GH, HH);
    ata_loss<<<dim3(GH / 128, GH / 128), 256, 0, stream>>>(w_expr, accum + 1, GH, HH);
  }

  // GRU recurrence: persistent cooperative kernel, line-granular flags
  {
    void* args[] = {(void*)&xi, (void*)&w_hh, (void*)&hn, (void*)&hsx, (void*)&flags};
    hipLaunchCooperativeKernel((void*)gru_persistent, dim3(256), dim3(512),
                               args, 0, stream);
  }

  token_kernel<<<NTOK, 256, 0, stream>>>(hsx, out_expr, out_cos, accum);

  final_kernel<<<(BB * GH + 255) / 256, 256, 0, stream>>>(hsx, out_cos, ema, accum,
                                                          out_mult, out_sel, out_hn,
                                                          out_sp, out_el);
}